// Round 3
// baseline (8724.356 us; speedup 1.0000x reference)
//
#include <hip/hip_runtime.h>
#include <hip/hip_bf16.h>
#include <math.h>

// Problem: T=128, IN=512, H=512, B=256, TAG=64, LM=200, POS=6, CAP=3
// This version: entire LSTM recurrence (128 steps) in ONE persistent kernel
// (128 blocks, plain launch — co-resident by capacity on 256 CUs), 2 grid
// barriers/step, ii2 pre-GEMM folded into the per-step GEMM via
// Wbig = [Wc | w_ii_perm | w_ti_perm] (K=1536).

typedef unsigned short u16;
using bf16x8 = __attribute__((ext_vector_type(8))) short;
using f32x4  = __attribute__((ext_vector_type(4))) float;
using u16x4  = __attribute__((ext_vector_type(4))) unsigned short;

#define LP 40   // LDS pitch for 32-wide k tiles (k_T / k_y)
#define LP2 72  // LDS pitch for 64-wide k tiles (k_rec phase A): 2-way bank alias only

__device__ __forceinline__ u16 f2b(float f){
  union{float f; unsigned u;} v; v.f=f;
  unsigned r = v.u + 0x7FFFu + ((v.u>>16)&1u);
  return (u16)(r>>16);
}
__device__ __forceinline__ float b2f(u16 h){
  union{float f; unsigned u;} v; v.u = ((unsigned)h)<<16; return v.f;
}

// stage a 128x32 bf16 tile (row-major, rowstride elems) into LDS [128][LP]
__device__ __forceinline__ void stage_tile(const u16* __restrict__ g, int row0, int k0,
                                           int rowstride, u16* l, int tid){
  #pragma unroll
  for(int id=tid; id<512; id+=256){
    int r=id>>2, c=id&3;
    *(uint4*)(&l[r*LP + c*8]) = *(const uint4*)(g + (size_t)(row0+r)*rowstride + k0 + c*8);
  }
}

__device__ __forceinline__ void mfma_tiles(const u16* lA, const u16* lB, f32x4 (&acc)[4][4],
                                           int mw, int nw, int l16, int quad){
  bf16x8 af[4], bfr[4];
  #pragma unroll
  for(int i=0;i<4;i++) af[i]  = *(const bf16x8*)(&lA[(mw+i*16+l16)*LP + quad*8]);
  #pragma unroll
  for(int j=0;j<4;j++) bfr[j] = *(const bf16x8*)(&lB[(nw+j*16+l16)*LP + quad*8]);
  #pragma unroll
  for(int i=0;i<4;i++)
    #pragma unroll
    for(int j=0;j<4;j++)
      acc[i][j] = __builtin_amdgcn_mfma_f32_16x16x32_bf16(af[i], bfr[j], acc[i][j], 0,0,0);
}

// custom monotonic grid barrier (all 128 blocks co-resident by capacity)
__device__ __forceinline__ void gridbar(unsigned* bar, unsigned target){
  __threadfence();            // release: make this block's stores visible at agent scope
  __syncthreads();
  if(threadIdx.x==0){
    __hip_atomic_fetch_add(bar, 1u, __ATOMIC_RELEASE, __HIP_MEMORY_SCOPE_AGENT);
    while(__hip_atomic_load(bar, __ATOMIC_RELAXED, __HIP_MEMORY_SCOPE_AGENT) < target)
      __builtin_amdgcn_s_sleep(1);
  }
  __syncthreads();
  __threadfence();            // acquire: invalidate caches before reading peers' data
}

// ---------------- W2 = w_ti @ w_ht  (1536x512), fp32 ----------------
__global__ __launch_bounds__(256) void k_w2(const float* __restrict__ w_ti,
                                            const float* __restrict__ w_ht,
                                            float* __restrict__ W2){
  __shared__ float lA[64*17];
  __shared__ float lB[16*68];
  int tid=threadIdx.x, tx=tid&15, ty=tid>>4;
  int r0=blockIdx.x*64, n0=blockIdx.y*64;
  float acc[4][4]={};
  for(int k0=0;k0<512;k0+=16){
    __syncthreads();
    { int row=tid>>2, c=(tid&3)*4;
      float4 v=*(const float4*)(w_ti + (size_t)(r0+row)*512 + k0 + c);
      lA[row*17+c]=v.x; lA[row*17+c+1]=v.y; lA[row*17+c+2]=v.z; lA[row*17+c+3]=v.w; }
    { int kk=tid>>4, c=(tid&15)*4;
      float4 v=*(const float4*)(w_ht + (size_t)(k0+kk)*512 + n0 + c);
      lB[kk*68+c]=v.x; lB[kk*68+c+1]=v.y; lB[kk*68+c+2]=v.z; lB[kk*68+c+3]=v.w; }
    __syncthreads();
    for(int kk=0;kk<16;kk++){
      float a[4],b[4];
      #pragma unroll
      for(int i=0;i<4;i++) a[i]=lA[(ty*4+i)*17+kk];
      #pragma unroll
      for(int j=0;j<4;j++) b[j]=lB[kk*68+tx*4+j];
      #pragma unroll
      for(int i=0;i<4;i++)
        #pragma unroll
        for(int j=0;j<4;j++) acc[i][j]+=a[i]*b[j];
    }
  }
  #pragma unroll
  for(int i=0;i<4;i++)
    #pragma unroll
    for(int j=0;j<4;j++)
      W2[(size_t)(r0+ty*4+i)*512 + n0+tx*4+j]=acc[i][j];
}

// ---------------- prep: Wbig + bf16 weight copies + state init + barrier reset ----------------
// Wbig[2048][1536] permuted rows m'=r*4+g:
//   cols [0,512)    = w_hi[g*512+r][:]  (+ W2[g*512+r][:] for g<3)      <- consumed vs h
//   cols [512,1024) = w_ii[g*512+r][:]                                   <- consumed vs x
//   cols [1024,1536)= g<3 ? w_ti[g*512+r][:] : 0                         <- consumed vs tadd2b
__global__ __launch_bounds__(256) void k_prep(
  const float* __restrict__ w_ii, const float* __restrict__ w_hi, const float* __restrict__ w_ti,
  const float* __restrict__ w_co, const float* __restrict__ w_ht,
  const float* __restrict__ wyf, const float* __restrict__ wyc,
  const float* __restrict__ h0, const float* __restrict__ c0, const float* __restrict__ t0,
  const float* __restrict__ W2,
  u16* __restrict__ Wbig, u16* __restrict__ wcob, u16* __restrict__ whtb, u16* __restrict__ wyb,
  u16* __restrict__ hseq0, u16* __restrict__ tadd2b0, float* __restrict__ c_state,
  unsigned* __restrict__ bar)
{
  int i=blockIdx.x*256+threadIdx.x;
  if(i<1048576){
    int m=i>>9, k=i&511, r=m>>2, g=m&3;
    float v=w_hi[(size_t)(g*512+r)*512+k];
    if(g<3) v+=W2[(size_t)(g*512+r)*512+k];
    size_t o=(size_t)m*1536+k;
    Wbig[o]      =f2b(v);
    Wbig[o+512]  =f2b(w_ii[(size_t)(g*512+r)*512+k]);
    Wbig[o+1024] =f2b(g<3 ? w_ti[(size_t)(g*512+r)*512+k] : 0.f);
  }
  if(i<262144){ wcob[i]=f2b(w_co[i]); whtb[i]=f2b(w_ht[i]); }
  if(i<32768){ wyb[i]=f2b(wyf[i]); wyb[32768+i]=f2b(wyc[i]); }
  if(i<131072){
    int b=i>>9, h=i&511;
    hseq0[(size_t)b*512+h]  =f2b(h0[(size_t)h*256+b]);   // h0^T (bf16, [b][h])
    tadd2b0[(size_t)b*512+h]=f2b(t0[(size_t)h*256+b]);   // slot0 carries t0 (ti_0 = w_ti@t0)
    c_state[i]=c0[i];
  }
  if(i==0) *bar=0u;                                      // reset grid barrier each replay
}

// ---------------- tadd[t] = w_lmt@lms + w_post@pos + w_capt@caps  (+ tadd2b[t+1]) ----------------
__global__ __launch_bounds__(256) void k_tadd(
  const float* __restrict__ lms, const float* __restrict__ pos, const float* __restrict__ caps,
  const float* __restrict__ w_lmt, const float* __restrict__ w_post, const float* __restrict__ w_capt,
  const float* __restrict__ b_i,
  u16* __restrict__ tadd_b, u16* __restrict__ tadd2b)
{
  __shared__ float lw[64*212];
  int t=blockIdx.y, h0=blockIdx.x*64, tid=threadIdx.x;
  for(int i=tid;i<64*200;i+=256){ int r=i/200, l=i-r*200; lw[r*212+l]    =w_lmt[(size_t)(h0+r)*200+l]; }
  for(int i=tid;i<64*6;  i+=256){ int r=i/6,   l=i-r*6;   lw[r*212+200+l]=w_post[(size_t)(h0+r)*6+l]; }
  for(int i=tid;i<64*3;  i+=256){ int r=i/3,   l=i-r*3;   lw[r*212+206+l]=w_capt[(size_t)(h0+r)*3+l]; }
  __syncthreads();
  int bx=(tid&63)*4, hy=(tid>>6)*16;
  float acc[16][4];
  #pragma unroll
  for(int j=0;j<16;j++){acc[j][0]=0;acc[j][1]=0;acc[j][2]=0;acc[j][3]=0;}
  const float* L=lms+(size_t)t*200*256;
  for(int l=0;l<200;l++){
    float4 v=*(const float4*)(L+(size_t)l*256+bx);
    #pragma unroll
    for(int j=0;j<16;j++){ float w=lw[(hy+j)*212+l];
      acc[j][0]+=w*v.x; acc[j][1]+=w*v.y; acc[j][2]+=w*v.z; acc[j][3]+=w*v.w; }
  }
  const float* P=pos+(size_t)t*6*256;
  for(int l=0;l<6;l++){
    float4 v=*(const float4*)(P+(size_t)l*256+bx);
    #pragma unroll
    for(int j=0;j<16;j++){ float w=lw[(hy+j)*212+200+l];
      acc[j][0]+=w*v.x; acc[j][1]+=w*v.y; acc[j][2]+=w*v.z; acc[j][3]+=w*v.w; }
  }
  const float* C=caps+(size_t)t*3*256;
  for(int l=0;l<3;l++){
    float4 v=*(const float4*)(C+(size_t)l*256+bx);
    #pragma unroll
    for(int j=0;j<16;j++){ float w=lw[(hy+j)*212+206+l];
      acc[j][0]+=w*v.x; acc[j][1]+=w*v.y; acc[j][2]+=w*v.z; acc[j][3]+=w*v.w; }
  }
  #pragma unroll
  for(int j=0;j<16;j++){
    int h=h0+hy+j;
    u16* d=tadd_b+(size_t)t*131072+(size_t)h*256+bx;
    d[0]=f2b(acc[j][0]); d[1]=f2b(acc[j][1]); d[2]=f2b(acc[j][2]); d[3]=f2b(acc[j][3]);
  }
  if(t<127){
    #pragma unroll
    for(int q=0;q<4;q++)
      #pragma unroll
      for(int j=0;j<16;j++){
        int h=h0+hy+j;
        tadd2b[(size_t)(t+1)*131072+(size_t)(bx+q)*512+h]=f2b(acc[j][q]+b_i[2048+h]);
      }
  }
}

// ---------------- x[t] = inputs + embeddings -> xb[t][b][i] bf16 ----------------
__global__ __launch_bounds__(256) void k_x(
  const float* __restrict__ inputs, const float* __restrict__ lms, const float* __restrict__ pos,
  const float* __restrict__ caps,
  const float* __restrict__ w_lmw, const float* __restrict__ w_posw, const float* __restrict__ w_capw,
  u16* __restrict__ xb)
{
  __shared__ float lw[64*212];
  int t=blockIdx.y, i0=blockIdx.x*64, tid=threadIdx.x;
  for(int i=tid;i<200*64;i+=256){ int l=i>>6, j=i&63; lw[j*212+l]    =w_lmw[(size_t)l*512+i0+j]; }
  for(int i=tid;i<6*64;  i+=256){ int l=i>>6, j=i&63; lw[j*212+200+l]=w_posw[(size_t)l*512+i0+j]; }
  for(int i=tid;i<3*64;  i+=256){ int l=i>>6, j=i&63; lw[j*212+206+l]=w_capw[(size_t)l*512+i0+j]; }
  __syncthreads();
  int bx=(tid&63)*4, hy=(tid>>6)*16;
  float acc[16][4];
  #pragma unroll
  for(int j=0;j<16;j++){acc[j][0]=0;acc[j][1]=0;acc[j][2]=0;acc[j][3]=0;}
  const float* L=lms+(size_t)t*200*256;
  for(int l=0;l<200;l++){
    float4 v=*(const float4*)(L+(size_t)l*256+bx);
    #pragma unroll
    for(int j=0;j<16;j++){ float w=lw[(hy+j)*212+l];
      acc[j][0]+=w*v.x; acc[j][1]+=w*v.y; acc[j][2]+=w*v.z; acc[j][3]+=w*v.w; }
  }
  const float* P=pos+(size_t)t*6*256;
  for(int l=0;l<6;l++){
    float4 v=*(const float4*)(P+(size_t)l*256+bx);
    #pragma unroll
    for(int j=0;j<16;j++){ float w=lw[(hy+j)*212+200+l];
      acc[j][0]+=w*v.x; acc[j][1]+=w*v.y; acc[j][2]+=w*v.z; acc[j][3]+=w*v.w; }
  }
  const float* C=caps+(size_t)t*3*256;
  for(int l=0;l<3;l++){
    float4 v=*(const float4*)(C+(size_t)l*256+bx);
    #pragma unroll
    for(int j=0;j<16;j++){ float w=lw[(hy+j)*212+206+l];
      acc[j][0]+=w*v.x; acc[j][1]+=w*v.y; acc[j][2]+=w*v.z; acc[j][3]+=w*v.w; }
  }
  #pragma unroll
  for(int j=0;j<16;j++){
    int ii=i0+hy+j;
    float4 inp=*(const float4*)(inputs+(size_t)t*131072+(size_t)ii*256+bx);
    acc[j][0]+=inp.x; acc[j][1]+=inp.y; acc[j][2]+=inp.z; acc[j][3]+=inp.w;
  }
  #pragma unroll
  for(int q=0;q<4;q++)
    #pragma unroll
    for(int j=0;j<16;j++){
      int ii=i0+hy+j;
      xb[(size_t)t*131072+(size_t)(bx+q)*512+ii]=f2b(acc[j][q]);
    }
}

// ---------------- persistent recurrence: all 128 timesteps, 2 grid barriers per step ----------------
// phase A (all 128 blocks, 64x64 tiles over 2048x256, K=1536):
//   pre = Wbig @ [x_t | tadd2b_t | h_{t-1}]^T + b  -> gates -> c_new, c_bT, preO
// phase B (all 128 blocks, 32x32 tiles over 512x256, K=512, direct-from-L2 fragments):
//   o = sigmoid(preO + w_co@c_new); h = o*tanh(c_new) -> hseq[t+1]
__global__ __launch_bounds__(256) void k_rec(
  const u16* __restrict__ Wbig, const u16* __restrict__ wcob,
  const u16* __restrict__ xb, const u16* __restrict__ tadd2b,
  const float* __restrict__ b_i,
  float* __restrict__ c_state, float* __restrict__ preO,
  u16* __restrict__ c_bT, u16* __restrict__ hseq,
  unsigned* __restrict__ bar)
{
  __shared__ alignas(16) u16 sA[2][64*LP2];
  __shared__ alignas(16) u16 sB[2][64*LP2];
  int tid=threadIdx.x, lane=tid&63, wid=tid>>6;
  int l16=lane&15, quad=lane>>4;
  int bid=blockIdx.x;
  // phase A tile (grid 32 x 4)
  int m0=(bid>>2)*64, n0=(bid&3)*64;
  int mw=(wid>>1)*32, nw=(wid&1)*32;
  // phase B tile (grid 16 x 8)
  int bm0=(bid>>3)*32, bn0=(bid&7)*32;
  int bmw=(wid>>1)*16, bnw=(wid&1)*16;
  // staging role: 64 rows x 64 cols, 2 x uint4 per thread per tile
  int sr=tid>>2, sc=(tid&3)*16;
  const u16* gA = Wbig + (size_t)(m0+sr)*1536 + sc;   // +Acol per chunk
  const u16* wa  = wcob + (size_t)(bm0+bmw+l16)*512;  // phase B A-fragment row
  const u16* cbr = c_bT + (size_t)(bn0+bnw+l16)*512;  // phase B B-fragment row
  unsigned ep=0;
  uint4 ra0,ra1,rb0,rb1;

  // prologue: chunk 0 of t=0 (segment 0 = x)
  { const u16* ga=gA+512;
    ra0=*(const uint4*)ga; ra1=*(const uint4*)(ga+8);
    const u16* gb=xb+(size_t)(n0+sr)*512+sc;
    rb0=*(const uint4*)gb; rb1=*(const uint4*)(gb+8); }

  for(int t=0;t<128;t++){
    const u16* xsrc=xb    +(size_t)t*131072;
    const u16* tsrc=tadd2b+(size_t)t*131072;
    const u16* hsrc=hseq  +(size_t)t*131072;
    f32x4 acc[2][2]={};
    // commit prefetched chunk 0
    *(uint4*)&sA[0][sr*LP2+sc]=ra0; *(uint4*)&sA[0][sr*LP2+sc+8]=ra1;
    *(uint4*)&sB[0][sr*LP2+sc]=rb0; *(uint4*)&sB[0][sr*LP2+sc+8]=rb1;
    __syncthreads();
    // 24 chunks of K=64: chunks 0-7 = x (Wbig cols 512..), 8-15 = tadd (cols 1024..), 16-23 = h (cols 0..)
    for(int c=0;c<24;c++){
      int cur=c&1;
      if(c<23){
        int cn=c+1, s=cn>>3, kk=(cn&7)*64;
        const u16* ga=gA + (s==0?512:(s==1?1024:0)) + kk;
        const u16* gb=(s==0?xsrc:(s==1?tsrc:hsrc)) + (size_t)(n0+sr)*512 + kk + sc;
        ra0=*(const uint4*)ga; ra1=*(const uint4*)(ga+8);
        rb0=*(const uint4*)gb; rb1=*(const uint4*)(gb+8);
      }
      const u16* lA=sA[cur]; const u16* lB=sB[cur];
      #pragma unroll
      for(int ks=0;ks<2;ks++){
        bf16x8 a0=*(const bf16x8*)&lA[(mw+l16)*LP2+ks*32+quad*8];
        bf16x8 a1=*(const bf16x8*)&lA[(mw+16+l16)*LP2+ks*32+quad*8];
        bf16x8 b0=*(const bf16x8*)&lB[(nw+l16)*LP2+ks*32+quad*8];
        bf16x8 b1=*(const bf16x8*)&lB[(nw+16+l16)*LP2+ks*32+quad*8];
        acc[0][0]=__builtin_amdgcn_mfma_f32_16x16x32_bf16(a0,b0,acc[0][0],0,0,0);
        acc[0][1]=__builtin_amdgcn_mfma_f32_16x16x32_bf16(a0,b1,acc[0][1],0,0,0);
        acc[1][0]=__builtin_amdgcn_mfma_f32_16x16x32_bf16(a1,b0,acc[1][0],0,0,0);
        acc[1][1]=__builtin_amdgcn_mfma_f32_16x16x32_bf16(a1,b1,acc[1][1],0,0,0);
      }
      if(c<23){
        int nxt=cur^1;
        *(uint4*)&sA[nxt][sr*LP2+sc]=ra0; *(uint4*)&sA[nxt][sr*LP2+sc+8]=ra1;
        *(uint4*)&sB[nxt][sr*LP2+sc]=rb0; *(uint4*)&sB[nxt][sr*LP2+sc+8]=rb1;
      }
      __syncthreads();
    }
    // epilogue A: permuted rows -> acc[i][j][0..3] = gates i,f,z,o of hidden unit rh
    #pragma unroll
    for(int i=0;i<2;i++){
      int rh=((m0+mw+i*16)>>2)+quad;
      float b0=b_i[rh], b1=b_i[512+rh], b2=b_i[1024+rh], b3=b_i[1536+rh];
      #pragma unroll
      for(int j=0;j<2;j++){
        int n=n0+nw+j*16+l16;
        float pi=acc[i][j][0]+b0;
        float pf=acc[i][j][1]+b1;
        float pz=acc[i][j][2]+b2;
        float po=acc[i][j][3]+b3;
        float ig=1.f/(1.f+__expf(-pi));
        float fg=1.f/(1.f+__expf(-pf));
        float zg=tanhf(pz);
        float cn=fg*c_state[(size_t)rh*256+n]+ig*zg;
        c_state[(size_t)rh*256+n]=cn;
        c_bT[(size_t)n*512+rh]=f2b(cn);
        preO[(size_t)rh*256+n]=po;
      }
    }
    gridbar(bar, 128u*(++ep));
    // phase B: o-GEMM, fragments straight from L2 (no LDS, no intra-block barriers)
    f32x4 o4={};
    #pragma unroll
    for(int k0=0;k0<512;k0+=32){
      bf16x8 a=*(const bf16x8*)(wa +k0+quad*8);
      bf16x8 b=*(const bf16x8*)(cbr+k0+quad*8);
      o4=__builtin_amdgcn_mfma_f32_16x16x32_bf16(a,b,o4,0,0,0);
    }
    { int n=bn0+bnw+l16, mb=bm0+bmw+quad*4;
      u16x4 hv;
      #pragma unroll
      for(int rr=0;rr<4;rr++){
        float po=preO[(size_t)(mb+rr)*256+n]+o4[rr];
        float o=1.f/(1.f+__expf(-po));
        hv[rr]=f2b(o*tanhf(c_state[(size_t)(mb+rr)*256+n]));
      }
      *(u16x4*)(hseq+(size_t)(t+1)*131072+(size_t)n*512+mb)=hv;
    }
    // prefetch chunk 0 of next step (x segment, independent of this step) before the barrier
    if(t<127){
      const u16* ga=gA+512;
      ra0=*(const uint4*)ga; ra1=*(const uint4*)(ga+8);
      const u16* gb=xb+(size_t)(t+1)*131072+(size_t)(n0+sr)*512+sc;
      rb0=*(const uint4*)gb; rb1=*(const uint4*)(gb+8);
    }
    gridbar(bar, 128u*(++ep));
  }
}

// ---------------- T[t] = w_ht@h_t + b4 + tadd[t] -> out Ts (B,T,H) ----------------
__global__ __launch_bounds__(256) void k_T(
  const u16* __restrict__ whtb, const u16* __restrict__ hseq,
  const u16* __restrict__ tadd_b, const float* __restrict__ b_i,
  float* __restrict__ outTs)
{
  __shared__ alignas(16) u16 lA[128*LP];
  __shared__ alignas(16) u16 lB[128*LP];
  int tid=threadIdx.x, lane=tid&63, wid=tid>>6;
  int mw=(wid>>1)*64, nw=(wid&1)*64, l16=lane&15, quad=lane>>4;
  int m0=blockIdx.x*128, n0=blockIdx.y*128, t=blockIdx.z;
  const u16* hb=hseq+(size_t)(t+1)*131072;
  f32x4 acc[4][4]={};
  for(int k0=0;k0<512;k0+=32){
    __syncthreads();
    stage_tile(whtb,m0,k0,512,lA,tid);
    stage_tile(hb,n0,k0,512,lB,tid);
    __syncthreads();
    mfma_tiles(lA,lB,acc,mw,nw,l16,quad);
  }
  #pragma unroll
  for(int i=0;i<4;i++)
    #pragma unroll
    for(int j=0;j<4;j++){
      int n=n0+nw+j*16+l16;
      #pragma unroll
      for(int rr=0;rr<4;rr++){
        int m=m0+mw+i*16+quad*4+rr;
        float v=acc[i][j][rr]+b_i[2048+m]+b2f(tadd_b[(size_t)t*131072+(size_t)m*256+n]);
        outTs[(size_t)n*65536+(size_t)t*512+m]=v;
      }
    }
}

// ---------------- y_fact / y_cond = [wyf;wyc] @ Ts[t] + bias ----------------
__global__ __launch_bounds__(256) void k_y(
  const u16* __restrict__ wyb, const float* __restrict__ Ts,
  const float* __restrict__ b_yf, const float* __restrict__ b_yc,
  float* __restrict__ oyf, float* __restrict__ oyc)
{
  __shared__ alignas(16) u16 lA[128*LP];
  __shared__ alignas(16) u16 lB[128*LP];
  int tid=threadIdx.x, lane=tid&63, wid=tid>>6;
  int mw=(wid>>1)*64, nw=(wid&1)*64, l16=lane&15, quad=lane>>4;
  int n0=blockIdx.x*128, t=blockIdx.y;
  f32x4 acc[4][4]={};
  for(int k0=0;k0<512;k0+=32){
    __syncthreads();
    stage_tile(wyb,0,k0,512,lA,tid);
    for(int id=tid;id<512;id+=256){
      int r=id>>2, c=(id&3)*8;
      const float* s=Ts + (size_t)(n0+r)*65536 + (size_t)t*512 + k0 + c;
      float4 v0=*(const float4*)s, v1=*(const float4*)(s+4);
      u16* d=&lB[r*LP+c];
      d[0]=f2b(v0.x); d[1]=f2b(v0.y); d[2]=f2b(v0.z); d[3]=f2b(v0.w);
      d[4]=f2b(v1.x); d[5]=f2b(v1.y); d[6]=f2b(v1.z); d[7]=f2b(v1.w);
    }
    __syncthreads();
    mfma_tiles(lA,lB,acc,mw,nw,l16,quad);
  }
  #pragma unroll
  for(int i=0;i<4;i++)
    #pragma unroll
    for(int j=0;j<4;j++){
      int n=n0+nw+j*16+l16;
      #pragma unroll
      for(int rr=0;rr<4;rr++){
        int m=mw+i*16+quad*4+rr;
        float v=acc[i][j][rr]+(m<64? b_yf[m] : b_yc[m-64]);
        if(m<64) oyf[(size_t)n*8192+(size_t)t*64+m]=v;
        else     oyc[(size_t)n*8192+(size_t)t*64+(m-64)]=v;
      }
    }
}

// ---------------- log_softmax over 64 tags, per (b,t), both tensors ----------------
__global__ __launch_bounds__(256) void k_sm(const float* __restrict__ ysrc, float* __restrict__ dst){
  int wid=blockIdx.x*4+(threadIdx.x>>6);
  int lane=threadIdx.x&63;
  int tensor=wid>>15, bt=wid&32767;
  const float* s=ysrc+(size_t)tensor*2097152+(size_t)bt*64;
  float v=s[lane];
  float m=v;
  #pragma unroll
  for(int o=32;o;o>>=1) m=fmaxf(m,__shfl_xor(m,o,64));
  float e=__expf(v-m), sum=e;
  #pragma unroll
  for(int o=32;o;o>>=1) sum+=__shfl_xor(sum,o,64);
  dst[(size_t)tensor*2097152+(size_t)bt*64+lane]=v-m-__logf(sum);
}

extern "C" void kernel_launch(void* const* d_in, const int* in_sizes, int n_in,
                              void* d_out, int out_size, void* d_ws, size_t ws_size,
                              hipStream_t stream) {
  const float* inputs=(const float*)d_in[0];
  const float* lms   =(const float*)d_in[1];
  const float* pos   =(const float*)d_in[2];
  const float* caps  =(const float*)d_in[3];
  const float* h0    =(const float*)d_in[4];
  const float* c0    =(const float*)d_in[5];
  const float* t0    =(const float*)d_in[6];
  const float* w_ii  =(const float*)d_in[7];
  const float* w_hi  =(const float*)d_in[8];
  const float* w_ti  =(const float*)d_in[9];
  const float* w_co  =(const float*)d_in[10];
  const float* w_ht  =(const float*)d_in[11];
  const float* b_i   =(const float*)d_in[12];
  const float* wyf   =(const float*)d_in[13];
  const float* b_yf  =(const float*)d_in[14];
  const float* wyc   =(const float*)d_in[15];
  const float* b_yc  =(const float*)d_in[16];
  const float* w_lmw =(const float*)d_in[17];
  const float* w_posw=(const float*)d_in[18];
  const float* w_capw=(const float*)d_in[19];
  const float* w_lmt =(const float*)d_in[20];
  const float* w_post=(const float*)d_in[21];
  const float* w_capt=(const float*)d_in[22];

  char* ws=(char*)d_ws;
  float*    W2     =(float*)   (ws+0);          // 3,145,728
  u16*      Wbig   =(u16*)     (ws+3145728);    // 6,291,456
  u16*      wcob   =(u16*)     (ws+9437184);    //   524,288
  u16*      whtb   =(u16*)     (ws+9961472);    //   524,288
  u16*      wyb    =(u16*)     (ws+10485760);   //   131,072
  float*    c_state=(float*)   (ws+10616832);   //   524,288
  float*    preO   =(float*)   (ws+11141120);   //   524,288
  u16*      c_bT   =(u16*)     (ws+11665408);   //   262,144
  unsigned* bar    =(unsigned*)(ws+11927552);   //       128
  u16*      xb     =(u16*)     (ws+11927680);   // 33,554,432
  u16*      tadd_b =(u16*)     (ws+45482112);   // 33,554,432
  u16*      tadd2b =(u16*)     (ws+79036544);   // 33,554,432
  u16*      hseq   =(u16*)     (ws+112590976);  // 33,816,576  [129][256][512] bf16; slot0=h0^T

  float* out=(float*)d_out;
  float* out_lf=out;
  float* out_yf=out+4194304;
  float* out_yc=out+6291456;
  float* out_Ts=out+8388608;

  k_w2  <<<dim3(24,8),256,0,stream>>>(w_ti,w_ht,W2);
  k_prep<<<4096,256,0,stream>>>(w_ii,w_hi,w_ti,w_co,w_ht,wyf,wyc,h0,c0,t0,W2,
                                Wbig,wcob,whtb,wyb,hseq,tadd2b,c_state,bar);
  k_tadd<<<dim3(8,128),256,0,stream>>>(lms,pos,caps,w_lmt,w_post,w_capt,b_i,tadd_b,tadd2b);
  k_x   <<<dim3(8,128),256,0,stream>>>(inputs,lms,pos,caps,w_lmw,w_posw,w_capw,xb);

  // plain launch: 128 blocks on 256 CUs -> co-resident by capacity (36KB LDS, 256 thr/blk)
  k_rec<<<dim3(128),256,0,stream>>>(Wbig,wcob,xb,tadd2b,b_i,c_state,preO,c_bT,hseq,bar);

  k_T<<<dim3(4,2,128),256,0,stream>>>(whtb,hseq,tadd_b,b_i,out_Ts);
  k_y<<<dim3(2,128),256,0,stream>>>(wyb,out_Ts,b_yf,b_yc,out_yf,out_yc);
  k_sm<<<16384,256,0,stream>>>(out_yf,out_lf);
}

// Round 5
// 3795.532 us; speedup vs baseline: 2.2986x; 2.2986x over previous
//
#include <hip/hip_runtime.h>
#include <hip/hip_bf16.h>
#include <math.h>

// Problem: T=128, IN=512, H=512, B=256, TAG=64, LM=200, POS=6, CAP=3
// Persistent-recurrence version: fence-free grid barrier.
// All cross-block data inside k_rec moves via system-scope (sc0 sc1) loads/
// stores that bypass the non-coherent per-XCD L2s, so the barrier needs NO
// __threadfence (which emits buffer_wbl2/buffer_inv = full L2 walks, ~30us/bar).

typedef unsigned short u16;
using bf16x8 = __attribute__((ext_vector_type(8))) short;
using f32x4  = __attribute__((ext_vector_type(4))) float;
using u16x4  = __attribute__((ext_vector_type(4))) unsigned short;

#define LP 40   // LDS pitch for 32-wide k tiles (k_T / k_y)
#define LP2 72  // LDS pitch for 64-wide k tiles (k_rec phase A)

__device__ __forceinline__ u16 f2b(float f){
  union{float f; unsigned u;} v; v.f=f;
  unsigned r = v.u + 0x7FFFu + ((v.u>>16)&1u);
  return (u16)(r>>16);
}
__device__ __forceinline__ float b2f(u16 h){
  union{float f; unsigned u;} v; v.u = ((unsigned)h)<<16; return v.f;
}

// ---- system-scope (coherence-point) access helpers: bypass L1/L2 ----
__device__ __forceinline__ void ldg4(uint4& d, const void* p){
  asm volatile("global_load_dwordx4 %0, %1, off sc0 sc1" : "=v"(d) : "v"(p));
}
__device__ __forceinline__ void ldg4_off(uint4& d, const void* p, int byteoff){
  asm volatile("global_load_dwordx4 %0, %1, off offset:%2 sc0 sc1" : "=v"(d) : "v"(p), "i"(byteoff));
}
__device__ __forceinline__ void ldg1f_off(float& d, const void* p, int byteoff){
  asm volatile("global_load_dword %0, %1, off offset:%2 sc0 sc1" : "=v"(d) : "v"(p), "i"(byteoff));
}
__device__ __forceinline__ void stg1f(void* p, float v){
  asm volatile("global_store_dword %0, %1, off sc0 sc1" :: "v"(p), "v"(v) : "memory");
}
__device__ __forceinline__ void stg1h(void* p, unsigned v){
  asm volatile("global_store_short %0, %1, off sc0 sc1" :: "v"(p), "v"(v) : "memory");
}
__device__ __forceinline__ void stg2(void* p, uint2 v){
  asm volatile("global_store_dwordx2 %0, %1, off sc0 sc1" :: "v"(p), "v"(v) : "memory");
}
// wait for ALL vmem (incl. asm-issued, which the compiler's waitcnt pass can't see)
__device__ __forceinline__ void vwait0(){
  asm volatile("s_waitcnt vmcnt(0)" ::: "memory");
  __builtin_amdgcn_sched_barrier(0);
}

// stage a 128x32 bf16 tile (row-major, rowstride elems) into LDS [128][LP]
__device__ __forceinline__ void stage_tile(const u16* __restrict__ g, int row0, int k0,
                                           int rowstride, u16* l, int tid){
  #pragma unroll
  for(int id=tid; id<512; id+=256){
    int r=id>>2, c=id&3;
    *(uint4*)(&l[r*LP + c*8]) = *(const uint4*)(g + (size_t)(row0+r)*rowstride + k0 + c*8);
  }
}

__device__ __forceinline__ void mfma_tiles(const u16* lA, const u16* lB, f32x4 (&acc)[4][4],
                                           int mw, int nw, int l16, int quad){
  bf16x8 af[4], bfr[4];
  #pragma unroll
  for(int i=0;i<4;i++) af[i]  = *(const bf16x8*)(&lA[(mw+i*16+l16)*LP + quad*8]);
  #pragma unroll
  for(int j=0;j<4;j++) bfr[j] = *(const bf16x8*)(&lB[(nw+j*16+l16)*LP + quad*8]);
  #pragma unroll
  for(int i=0;i<4;i++)
    #pragma unroll
    for(int j=0;j<4;j++)
      acc[i][j] = __builtin_amdgcn_mfma_f32_16x16x32_bf16(af[i], bfr[j], acc[i][j], 0,0,0);
}

// fence-free monotonic grid barrier. Data exchanged around it uses sc0/sc1
// bypass accesses, so no cache maintenance is required here.
__device__ __forceinline__ void gridbar(unsigned* bar, unsigned target){
  vwait0();                   // my coherent stores are ack'd at the coherence point
  __syncthreads();
  if(threadIdx.x==0){
    __hip_atomic_fetch_add(bar, 1u, __ATOMIC_RELAXED, __HIP_MEMORY_SCOPE_AGENT);
    while(__hip_atomic_load(bar, __ATOMIC_RELAXED, __HIP_MEMORY_SCOPE_AGENT) < target)
      __builtin_amdgcn_s_sleep(4);
  }
  __syncthreads();
}

// ---------------- W2 = w_ti @ w_ht  (1536x512), fp32 ----------------
__global__ __launch_bounds__(256) void k_w2(const float* __restrict__ w_ti,
                                            const float* __restrict__ w_ht,
                                            float* __restrict__ W2){
  __shared__ float lA[64*17];
  __shared__ float lB[16*68];
  int tid=threadIdx.x, tx=tid&15, ty=tid>>4;
  int r0=blockIdx.x*64, n0=blockIdx.y*64;
  float acc[4][4]={};
  for(int k0=0;k0<512;k0+=16){
    __syncthreads();
    { int row=tid>>2, c=(tid&3)*4;
      float4 v=*(const float4*)(w_ti + (size_t)(r0+row)*512 + k0 + c);
      lA[row*17+c]=v.x; lA[row*17+c+1]=v.y; lA[row*17+c+2]=v.z; lA[row*17+c+3]=v.w; }
    { int kk=tid>>4, c=(tid&15)*4;
      float4 v=*(const float4*)(w_ht + (size_t)(k0+kk)*512 + n0 + c);
      lB[kk*68+c]=v.x; lB[kk*68+c+1]=v.y; lB[kk*68+c+2]=v.z; lB[kk*68+c+3]=v.w; }
    __syncthreads();
    for(int kk=0;kk<16;kk++){
      float a[4],b[4];
      #pragma unroll
      for(int i=0;i<4;i++) a[i]=lA[(ty*4+i)*17+kk];
      #pragma unroll
      for(int j=0;j<4;j++) b[j]=lB[kk*68+tx*4+j];
      #pragma unroll
      for(int i=0;i<4;i++)
        #pragma unroll
        for(int j=0;j<4;j++) acc[i][j]+=a[i]*b[j];
    }
  }
  #pragma unroll
  for(int i=0;i<4;i++)
    #pragma unroll
    for(int j=0;j<4;j++)
      W2[(size_t)(r0+ty*4+i)*512 + n0+tx*4+j]=acc[i][j];
}

// ---------------- prep: Wbig + bf16 weight copies + state init + barrier reset ----------------
__global__ __launch_bounds__(256) void k_prep(
  const float* __restrict__ w_ii, const float* __restrict__ w_hi, const float* __restrict__ w_ti,
  const float* __restrict__ w_co, const float* __restrict__ w_ht,
  const float* __restrict__ wyf, const float* __restrict__ wyc,
  const float* __restrict__ h0, const float* __restrict__ c0, const float* __restrict__ t0,
  const float* __restrict__ W2,
  u16* __restrict__ Wbig, u16* __restrict__ wcob, u16* __restrict__ whtb, u16* __restrict__ wyb,
  u16* __restrict__ hseq0, u16* __restrict__ tadd2b0, float* __restrict__ c_state,
  unsigned* __restrict__ bar)
{
  int i=blockIdx.x*256+threadIdx.x;
  if(i<1048576){
    int m=i>>9, k=i&511, r=m>>2, g=m&3;
    float v=w_hi[(size_t)(g*512+r)*512+k];
    if(g<3) v+=W2[(size_t)(g*512+r)*512+k];
    size_t o=(size_t)m*1536+k;
    Wbig[o]      =f2b(v);
    Wbig[o+512]  =f2b(w_ii[(size_t)(g*512+r)*512+k]);
    Wbig[o+1024] =f2b(g<3 ? w_ti[(size_t)(g*512+r)*512+k] : 0.f);
  }
  if(i<262144){ wcob[i]=f2b(w_co[i]); whtb[i]=f2b(w_ht[i]); }
  if(i<32768){ wyb[i]=f2b(wyf[i]); wyb[32768+i]=f2b(wyc[i]); }
  if(i<131072){
    int b=i>>9, h=i&511;
    hseq0[(size_t)b*512+h]  =f2b(h0[(size_t)h*256+b]);   // h0^T (bf16, [b][h])
    tadd2b0[(size_t)b*512+h]=f2b(t0[(size_t)h*256+b]);   // slot0 carries t0
    c_state[i]=c0[i];
  }
  if(i==0) *bar=0u;
}

// ---------------- tadd[t] ----------------
__global__ __launch_bounds__(256) void k_tadd(
  const float* __restrict__ lms, const float* __restrict__ pos, const float* __restrict__ caps,
  const float* __restrict__ w_lmt, const float* __restrict__ w_post, const float* __restrict__ w_capt,
  const float* __restrict__ b_i,
  u16* __restrict__ tadd_b, u16* __restrict__ tadd2b)
{
  __shared__ float lw[64*212];
  int t=blockIdx.y, h0=blockIdx.x*64, tid=threadIdx.x;
  for(int i=tid;i<64*200;i+=256){ int r=i/200, l=i-r*200; lw[r*212+l]    =w_lmt[(size_t)(h0+r)*200+l]; }
  for(int i=tid;i<64*6;  i+=256){ int r=i/6,   l=i-r*6;   lw[r*212+200+l]=w_post[(size_t)(h0+r)*6+l]; }
  for(int i=tid;i<64*3;  i+=256){ int r=i/3,   l=i-r*3;   lw[r*212+206+l]=w_capt[(size_t)(h0+r)*3+l]; }
  __syncthreads();
  int bx=(tid&63)*4, hy=(tid>>6)*16;
  float acc[16][4];
  #pragma unroll
  for(int j=0;j<16;j++){acc[j][0]=0;acc[j][1]=0;acc[j][2]=0;acc[j][3]=0;}
  const float* L=lms+(size_t)t*200*256;
  for(int l=0;l<200;l++){
    float4 v=*(const float4*)(L+(size_t)l*256+bx);
    #pragma unroll
    for(int j=0;j<16;j++){ float w=lw[(hy+j)*212+l];
      acc[j][0]+=w*v.x; acc[j][1]+=w*v.y; acc[j][2]+=w*v.z; acc[j][3]+=w*v.w; }
  }
  const float* P=pos+(size_t)t*6*256;
  for(int l=0;l<6;l++){
    float4 v=*(const float4*)(P+(size_t)l*256+bx);
    #pragma unroll
    for(int j=0;j<16;j++){ float w=lw[(hy+j)*212+200+l];
      acc[j][0]+=w*v.x; acc[j][1]+=w*v.y; acc[j][2]+=w*v.z; acc[j][3]+=w*v.w; }
  }
  const float* C=caps+(size_t)t*3*256;
  for(int l=0;l<3;l++){
    float4 v=*(const float4*)(C+(size_t)l*256+bx);
    #pragma unroll
    for(int j=0;j<16;j++){ float w=lw[(hy+j)*212+206+l];
      acc[j][0]+=w*v.x; acc[j][1]+=w*v.y; acc[j][2]+=w*v.z; acc[j][3]+=w*v.w; }
  }
  #pragma unroll
  for(int j=0;j<16;j++){
    int h=h0+hy+j;
    u16* d=tadd_b+(size_t)t*131072+(size_t)h*256+bx;
    d[0]=f2b(acc[j][0]); d[1]=f2b(acc[j][1]); d[2]=f2b(acc[j][2]); d[3]=f2b(acc[j][3]);
  }
  if(t<127){
    #pragma unroll
    for(int q=0;q<4;q++)
      #pragma unroll
      for(int j=0;j<16;j++){
        int h=h0+hy+j;
        tadd2b[(size_t)(t+1)*131072+(size_t)(bx+q)*512+h]=f2b(acc[j][q]+b_i[2048+h]);
      }
  }
}

// ---------------- x[t] ----------------
__global__ __launch_bounds__(256) void k_x(
  const float* __restrict__ inputs, const float* __restrict__ lms, const float* __restrict__ pos,
  const float* __restrict__ caps,
  const float* __restrict__ w_lmw, const float* __restrict__ w_posw, const float* __restrict__ w_capw,
  u16* __restrict__ xb)
{
  __shared__ float lw[64*212];
  int t=blockIdx.y, i0=blockIdx.x*64, tid=threadIdx.x;
  for(int i=tid;i<200*64;i+=256){ int l=i>>6, j=i&63; lw[j*212+l]    =w_lmw[(size_t)l*512+i0+j]; }
  for(int i=tid;i<6*64;  i+=256){ int l=i>>6, j=i&63; lw[j*212+200+l]=w_posw[(size_t)l*512+i0+j]; }
  for(int i=tid;i<3*64;  i+=256){ int l=i>>6, j=i&63; lw[j*212+206+l]=w_capw[(size_t)l*512+i0+j]; }
  __syncthreads();
  int bx=(tid&63)*4, hy=(tid>>6)*16;
  float acc[16][4];
  #pragma unroll
  for(int j=0;j<16;j++){acc[j][0]=0;acc[j][1]=0;acc[j][2]=0;acc[j][3]=0;}
  const float* L=lms+(size_t)t*200*256;
  for(int l=0;l<200;l++){
    float4 v=*(const float4*)(L+(size_t)l*256+bx);
    #pragma unroll
    for(int j=0;j<16;j++){ float w=lw[(hy+j)*212+l];
      acc[j][0]+=w*v.x; acc[j][1]+=w*v.y; acc[j][2]+=w*v.z; acc[j][3]+=w*v.w; }
  }
  const float* P=pos+(size_t)t*6*256;
  for(int l=0;l<6;l++){
    float4 v=*(const float4*)(P+(size_t)l*256+bx);
    #pragma unroll
    for(int j=0;j<16;j++){ float w=lw[(hy+j)*212+200+l];
      acc[j][0]+=w*v.x; acc[j][1]+=w*v.y; acc[j][2]+=w*v.z; acc[j][3]+=w*v.w; }
  }
  const float* C=caps+(size_t)t*3*256;
  for(int l=0;l<3;l++){
    float4 v=*(const float4*)(C+(size_t)l*256+bx);
    #pragma unroll
    for(int j=0;j<16;j++){ float w=lw[(hy+j)*212+206+l];
      acc[j][0]+=w*v.x; acc[j][1]+=w*v.y; acc[j][2]+=w*v.z; acc[j][3]+=w*v.w; }
  }
  #pragma unroll
  for(int j=0;j<16;j++){
    int ii=i0+hy+j;
    float4 inp=*(const float4*)(inputs+(size_t)t*131072+(size_t)ii*256+bx);
    acc[j][0]+=inp.x; acc[j][1]+=inp.y; acc[j][2]+=inp.z; acc[j][3]+=inp.w;
  }
  #pragma unroll
  for(int q=0;q<4;q++)
    #pragma unroll
    for(int j=0;j<16;j++){
      int ii=i0+hy+j;
      xb[(size_t)t*131072+(size_t)(bx+q)*512+ii]=f2b(acc[j][q]);
    }
}

// ---------------- persistent recurrence ----------------
// phase A (128 blocks, 64x64 tiles over 2048x256, K=1536):
//   pre = Wbig @ [x_t | tadd2b_t | h_{t-1}]^T + b -> gates -> c (regs) -> c_bT/c_state/preO (coherent)
// phase B (128 blocks, 32x32 tiles over 512x256, K=512, coherent fragments):
//   o = sigmoid(preO + w_co@c_new); h = o*tanh(c) -> hseq[t+1] (coherent)
__global__ __launch_bounds__(256) void k_rec(
  const u16* __restrict__ Wbig, const u16* __restrict__ wcob,
  const u16* __restrict__ xb, const u16* __restrict__ tadd2b,
  const float* __restrict__ b_i,
  float* __restrict__ c_state, float* __restrict__ preO,
  u16* __restrict__ c_bT, u16* __restrict__ hseq,
  unsigned* __restrict__ bar)
{
  __shared__ alignas(16) u16 sA[2][64*LP2];
  __shared__ alignas(16) u16 sB[2][64*LP2];
  int tid=threadIdx.x, lane=tid&63, wid=tid>>6;
  int l16=lane&15, quad=lane>>4;
  int bid=blockIdx.x;
  // phase A tile (grid 32 x 4)
  int m0=(bid>>2)*64, n0=(bid&3)*64;
  int mw=(wid>>1)*32, nw=(wid&1)*32;
  // phase B tile (grid 16 x 8)
  int bm0=(bid>>3)*32, bn0=(bid&7)*32;
  int bmw=(wid>>1)*16, bnw=(wid&1)*16;
  int nB=bn0+bnw+l16, mB=bm0+bmw+quad*4;
  // staging role
  int sr=tid>>2, sc=(tid&3)*16;
  const u16* gA  = Wbig + (size_t)(m0+sr)*1536 + sc;
  const u16* wa  = wcob + (size_t)(bm0+bmw+l16)*512;
  const u16* cbr = c_bT + (size_t)(bn0+bnw+l16)*512;

  // fp32 cell state lives in registers (same block owns the same tile every step)
  float creg[2][2];
  #pragma unroll
  for(int i=0;i<2;i++){
    int rh=((m0+mw+i*16)>>2)+quad;
    #pragma unroll
    for(int j=0;j<2;j++) creg[i][j]=c_state[(size_t)rh*256 + (n0+nw+j*16+l16)];
  }

  unsigned ep=0;
  uint4 ra0,ra1,rb0,rb1;
  { const u16* ga=gA+512;
    ra0=*(const uint4*)ga; ra1=*(const uint4*)(ga+8);
    const u16* gb=xb+(size_t)(n0+sr)*512+sc;
    rb0=*(const uint4*)gb; rb1=*(const uint4*)(gb+8); }

  for(int t=0;t<128;t++){
    const u16* xsrc=xb    +(size_t)t*131072;
    const u16* tsrc=tadd2b+(size_t)t*131072;
    const u16* hsrc=hseq  +(size_t)t*131072;
    f32x4 acc[2][2]={};
    *(uint4*)&sA[0][sr*LP2+sc]=ra0; *(uint4*)&sA[0][sr*LP2+sc+8]=ra1;
    *(uint4*)&sB[0][sr*LP2+sc]=rb0; *(uint4*)&sB[0][sr*LP2+sc+8]=rb1;
    __syncthreads();
    // 24 chunks of K=64: 0-7 = x (Wbig cols 512..), 8-15 = tadd (1024..), 16-23 = h (0..)
    for(int c=0;c<24;c++){
      int cur=c&1;
      if(c<23){
        int cn=c+1, s=cn>>3, kk=(cn&7)*64;
        const u16* ga=gA + (s==0?512:(s==1?1024:0)) + kk;
        ra0=*(const uint4*)ga; ra1=*(const uint4*)(ga+8);
        const u16* gb=(s==0?xsrc:(s==1?tsrc:hsrc)) + (size_t)(n0+sr)*512 + kk + sc;
        if(s<2){ rb0=*(const uint4*)gb; rb1=*(const uint4*)(gb+8); }
        else   { ldg4(rb0, gb); ldg4(rb1, gb+8); }   // h is cross-block: bypass L2
      }
      const u16* lA=sA[cur]; const u16* lB=sB[cur];
      #pragma unroll
      for(int ks=0;ks<2;ks++){
        bf16x8 a0=*(const bf16x8*)&lA[(mw+l16)*LP2+ks*32+quad*8];
        bf16x8 a1=*(const bf16x8*)&lA[(mw+16+l16)*LP2+ks*32+quad*8];
        bf16x8 b0=*(const bf16x8*)&lB[(nw+l16)*LP2+ks*32+quad*8];
        bf16x8 b1=*(const bf16x8*)&lB[(nw+16+l16)*LP2+ks*32+quad*8];
        acc[0][0]=__builtin_amdgcn_mfma_f32_16x16x32_bf16(a0,b0,acc[0][0],0,0,0);
        acc[0][1]=__builtin_amdgcn_mfma_f32_16x16x32_bf16(a0,b1,acc[0][1],0,0,0);
        acc[1][0]=__builtin_amdgcn_mfma_f32_16x16x32_bf16(a1,b0,acc[1][0],0,0,0);
        acc[1][1]=__builtin_amdgcn_mfma_f32_16x16x32_bf16(a1,b1,acc[1][1],0,0,0);
      }
      if(c<23){
        vwait0();   // asm loads aren't tracked by the compiler's waitcnt pass
        int nxt=cur^1;
        *(uint4*)&sA[nxt][sr*LP2+sc]=ra0; *(uint4*)&sA[nxt][sr*LP2+sc+8]=ra1;
        *(uint4*)&sB[nxt][sr*LP2+sc]=rb0; *(uint4*)&sB[nxt][sr*LP2+sc+8]=rb1;
      }
      __syncthreads();
    }
    // epilogue A: acc[i][j][0..3] = gates i,f,z,o of hidden unit rh (permuted rows)
    #pragma unroll
    for(int i=0;i<2;i++){
      int rh=((m0+mw+i*16)>>2)+quad;
      float b0=b_i[rh], b1=b_i[512+rh], b2=b_i[1024+rh], b3=b_i[1536+rh];
      #pragma unroll
      for(int j=0;j<2;j++){
        int n=n0+nw+j*16+l16;
        float pi=acc[i][j][0]+b0;
        float pf=acc[i][j][1]+b1;
        float pz=acc[i][j][2]+b2;
        float po=acc[i][j][3]+b3;
        float ig=1.f/(1.f+__expf(-pi));
        float fg=1.f/(1.f+__expf(-pf));
        float zg=tanhf(pz);
        float cn_=fg*creg[i][j]+ig*zg;
        creg[i][j]=cn_;
        stg1f(c_state+(size_t)rh*256+n, cn_);
        stg1h(c_bT+(size_t)n*512+rh, (unsigned)f2b(cn_));
        stg1f(preO+(size_t)rh*256+n, po);
      }
    }
    gridbar(bar, 128u*(++ep));
    // phase B: o-GEMM from coherence point (no LDS)
    float pre4[4], cc4[4];
    { const float* pb=preO   +(size_t)mB*256+nB;
      const float* cb=c_state+(size_t)mB*256+nB;
      ldg1f_off(pre4[0],pb,0); ldg1f_off(pre4[1],pb,1024);
      ldg1f_off(pre4[2],pb,2048); ldg1f_off(pre4[3],pb,3072);
      ldg1f_off(cc4[0],cb,0); ldg1f_off(cc4[1],cb,1024);
      ldg1f_off(cc4[2],cb,2048); ldg1f_off(cc4[3],cb,3072); }
    f32x4 o4={};
    const u16* cq=cbr+quad*8;
    #pragma unroll
    for(int half=0; half<2; half++){
      uint4 cb8[8];
      #pragma unroll
      for(int q8=0;q8<8;q8++) ldg4_off(cb8[q8], cq, (half*256+q8*32)*2);
      vwait0();
      #pragma unroll
      for(int q8=0;q8<8;q8++){
        bf16x8 a=*(const bf16x8*)(wa + half*256 + q8*32 + quad*8);
        o4=__builtin_amdgcn_mfma_f32_16x16x32_bf16(a, *(bf16x8*)&cb8[q8], o4, 0,0,0);
      }
    }
    { u16x4 hv;
      #pragma unroll
      for(int rr=0;rr<4;rr++){
        float po=pre4[rr]+o4[rr];
        float o=1.f/(1.f+__expf(-po));
        hv[rr]=f2b(o*tanhf(cc4[rr]));
      }
      stg2(hseq+(size_t)(t+1)*131072+(size_t)nB*512+mB, *(uint2*)&hv);
    }
    // prefetch chunk 0 of next step (x segment, stable data) before the barrier
    if(t<127){
      const u16* ga=gA+512;
      ra0=*(const uint4*)ga; ra1=*(const uint4*)(ga+8);
      const u16* gb=xb+(size_t)(t+1)*131072+(size_t)(n0+sr)*512+sc;
      rb0=*(const uint4*)gb; rb1=*(const uint4*)(gb+8);
    }
    gridbar(bar, 128u*(++ep));
  }
}

// ---------------- T[t] = w_ht@h_t + b4 + tadd[t] -> out Ts (B,T,H) ----------------
__global__ __launch_bounds__(256) void k_T(
  const u16* __restrict__ whtb, const u16* __restrict__ hseq,
  const u16* __restrict__ tadd_b, const float* __restrict__ b_i,
  float* __restrict__ outTs)
{
  __shared__ alignas(16) u16 lA[128*LP];
  __shared__ alignas(16) u16 lB[128*LP];
  int tid=threadIdx.x, lane=tid&63, wid=tid>>6;
  int mw=(wid>>1)*64, nw=(wid&1)*64, l16=lane&15, quad=lane>>4;
  int m0=blockIdx.x*128, n0=blockIdx.y*128, t=blockIdx.z;
  const u16* hb=hseq+(size_t)(t+1)*131072;
  f32x4 acc[4][4]={};
  for(int k0=0;k0<512;k0+=32){
    __syncthreads();
    stage_tile(whtb,m0,k0,512,lA,tid);
    stage_tile(hb,n0,k0,512,lB,tid);
    __syncthreads();
    mfma_tiles(lA,lB,acc,mw,nw,l16,quad);
  }
  #pragma unroll
  for(int i=0;i<4;i++)
    #pragma unroll
    for(int j=0;j<4;j++){
      int n=n0+nw+j*16+l16;
      #pragma unroll
      for(int rr=0;rr<4;rr++){
        int m=m0+mw+i*16+quad*4+rr;
        float v=acc[i][j][rr]+b_i[2048+m]+b2f(tadd_b[(size_t)t*131072+(size_t)m*256+n]);
        outTs[(size_t)n*65536+(size_t)t*512+m]=v;
      }
    }
}

// ---------------- y_fact / y_cond ----------------
__global__ __launch_bounds__(256) void k_y(
  const u16* __restrict__ wyb, const float* __restrict__ Ts,
  const float* __restrict__ b_yf, const float* __restrict__ b_yc,
  float* __restrict__ oyf, float* __restrict__ oyc)
{
  __shared__ alignas(16) u16 lA[128*LP];
  __shared__ alignas(16) u16 lB[128*LP];
  int tid=threadIdx.x, lane=tid&63, wid=tid>>6;
  int mw=(wid>>1)*64, nw=(wid&1)*64, l16=lane&15, quad=lane>>4;
  int n0=blockIdx.x*128, t=blockIdx.y;
  f32x4 acc[4][4]={};
  for(int k0=0;k0<512;k0+=32){
    __syncthreads();
    stage_tile(wyb,0,k0,512,lA,tid);
    for(int id=tid;id<512;id+=256){
      int r=id>>2, c=(id&3)*8;
      const float* s=Ts + (size_t)(n0+r)*65536 + (size_t)t*512 + k0 + c;
      float4 v0=*(const float4*)s, v1=*(const float4*)(s+4);
      u16* d=&lB[r*LP+c];
      d[0]=f2b(v0.x); d[1]=f2b(v0.y); d[2]=f2b(v0.z); d[3]=f2b(v0.w);
      d[4]=f2b(v1.x); d[5]=f2b(v1.y); d[6]=f2b(v1.z); d[7]=f2b(v1.w);
    }
    __syncthreads();
    mfma_tiles(lA,lB,acc,mw,nw,l16,quad);
  }
  #pragma unroll
  for(int i=0;i<4;i++)
    #pragma unroll
    for(int j=0;j<4;j++){
      int n=n0+nw+j*16+l16;
      #pragma unroll
      for(int rr=0;rr<4;rr++){
        int m=mw+i*16+quad*4+rr;
        float v=acc[i][j][rr]+(m<64? b_yf[m] : b_yc[m-64]);
        if(m<64) oyf[(size_t)n*8192+(size_t)t*64+m]=v;
        else     oyc[(size_t)n*8192+(size_t)t*64+(m-64)]=v;
      }
    }
}

// ---------------- log_softmax over 64 tags ----------------
__global__ __launch_bounds__(256) void k_sm(const float* __restrict__ ysrc, float* __restrict__ dst){
  int wid=blockIdx.x*4+(threadIdx.x>>6);
  int lane=threadIdx.x&63;
  int tensor=wid>>15, bt=wid&32767;
  const float* s=ysrc+(size_t)tensor*2097152+(size_t)bt*64;
  float v=s[lane];
  float m=v;
  #pragma unroll
  for(int o=32;o;o>>=1) m=fmaxf(m,__shfl_xor(m,o,64));
  float e=__expf(v-m), sum=e;
  #pragma unroll
  for(int o=32;o;o>>=1) sum+=__shfl_xor(sum,o,64);
  dst[(size_t)tensor*2097152+(size_t)bt*64+lane]=v-m-__logf(sum);
}

extern "C" void kernel_launch(void* const* d_in, const int* in_sizes, int n_in,
                              void* d_out, int out_size, void* d_ws, size_t ws_size,
                              hipStream_t stream) {
  const float* inputs=(const float*)d_in[0];
  const float* lms   =(const float*)d_in[1];
  const float* pos   =(const float*)d_in[2];
  const float* caps  =(const float*)d_in[3];
  const float* h0    =(const float*)d_in[4];
  const float* c0    =(const float*)d_in[5];
  const float* t0    =(const float*)d_in[6];
  const float* w_ii  =(const float*)d_in[7];
  const float* w_hi  =(const float*)d_in[8];
  const float* w_ti  =(const float*)d_in[9];
  const float* w_co  =(const float*)d_in[10];
  const float* w_ht  =(const float*)d_in[11];
  const float* b_i   =(const float*)d_in[12];
  const float* wyf   =(const float*)d_in[13];
  const float* b_yf  =(const float*)d_in[14];
  const float* wyc   =(const float*)d_in[15];
  const float* b_yc  =(const float*)d_in[16];
  const float* w_lmw =(const float*)d_in[17];
  const float* w_posw=(const float*)d_in[18];
  const float* w_capw=(const float*)d_in[19];
  const float* w_lmt =(const float*)d_in[20];
  const float* w_post=(const float*)d_in[21];
  const float* w_capt=(const float*)d_in[22];

  char* ws=(char*)d_ws;
  float*    W2     =(float*)   (ws+0);          // 3,145,728
  u16*      Wbig   =(u16*)     (ws+3145728);    // 6,291,456
  u16*      wcob   =(u16*)     (ws+9437184);    //   524,288
  u16*      whtb   =(u16*)     (ws+9961472);    //   524,288
  u16*      wyb    =(u16*)     (ws+10485760);   //   131,072
  float*    c_state=(float*)   (ws+10616832);   //   524,288
  float*    preO   =(float*)   (ws+11141120);   //   524,288
  u16*      c_bT   =(u16*)     (ws+11665408);   //   262,144
  unsigned* bar    =(unsigned*)(ws+11927552);   //       128
  u16*      xb     =(u16*)     (ws+11927680);   // 33,554,432
  u16*      tadd_b =(u16*)     (ws+45482112);   // 33,554,432
  u16*      tadd2b =(u16*)     (ws+79036544);   // 33,554,432
  u16*      hseq   =(u16*)     (ws+112590976);  // 33,816,576  [129][256][512]; slot0=h0^T

  float* out=(float*)d_out;
  float* out_lf=out;
  float* out_yf=out+4194304;
  float* out_yc=out+6291456;
  float* out_Ts=out+8388608;

  k_w2  <<<dim3(24,8),256,0,stream>>>(w_ti,w_ht,W2);
  k_prep<<<4096,256,0,stream>>>(w_ii,w_hi,w_ti,w_co,w_ht,wyf,wyc,h0,c0,t0,W2,
                                Wbig,wcob,whtb,wyb,hseq,tadd2b,c_state,bar);
  k_tadd<<<dim3(8,128),256,0,stream>>>(lms,pos,caps,w_lmt,w_post,w_capt,b_i,tadd_b,tadd2b);
  k_x   <<<dim3(8,128),256,0,stream>>>(inputs,lms,pos,caps,w_lmw,w_posw,w_capw,xb);

  // plain launch: 128 blocks on 256 CUs -> co-resident by capacity
  k_rec<<<dim3(128),256,0,stream>>>(Wbig,wcob,xb,tadd2b,b_i,c_state,preO,c_bT,hseq,bar);

  k_T<<<dim3(4,2,128),256,0,stream>>>(whtb,hseq,tadd_b,b_i,out_Ts);
  k_y<<<dim3(2,128),256,0,stream>>>(wyb,out_Ts,b_yf,b_yc,out_yf,out_yc);
  k_sm<<<16384,256,0,stream>>>(out_yf,out_lf);
}

// Round 6
// 2918.288 us; speedup vs baseline: 2.9895x; 1.3006x over previous
//
#include <hip/hip_runtime.h>
#include <hip/hip_bf16.h>
#include <math.h>

// Problem: T=128, IN=512, H=512, B=256, TAG=64, LM=200, POS=6, CAP=3
// Persistent recurrence, round 6: counted-vmcnt depth-2 staging pipeline
// (BK=128, 12 chunks), raw s_barrier (no vmcnt drain) inside the K-loop,
// all in-loop vmem as ordered inline-asm, w_co in LDS, b_i/c in registers.

typedef unsigned short u16;
using bf16x8 = __attribute__((ext_vector_type(8))) short;
using f32x4  = __attribute__((ext_vector_type(4))) float;
using u16x4  = __attribute__((ext_vector_type(4))) unsigned short;

#define LP 40    // LDS pitch for 32-wide k tiles (k_T / k_y)
#define LP3 136  // LDS pitch for 128-wide k chunks (k_rec phase A)

__device__ __forceinline__ u16 f2b(float f){
  union{float f; unsigned u;} v; v.f=f;
  unsigned r = v.u + 0x7FFFu + ((v.u>>16)&1u);
  return (u16)(r>>16);
}
__device__ __forceinline__ float b2f(u16 h){
  union{float f; unsigned u;} v; v.u = ((unsigned)h)<<16; return v.f;
}

// ---- counted-wait / barrier primitives ----
#define VMCNT(n) do{ asm volatile("s_waitcnt vmcnt(" #n ")" ::: "memory"); \
                     __builtin_amdgcn_sched_barrier(0); }while(0)
#define LBAR()   do{ asm volatile("s_waitcnt lgkmcnt(0)" ::: "memory"); \
                     __builtin_amdgcn_sched_barrier(0); \
                     __builtin_amdgcn_s_barrier(); \
                     __builtin_amdgcn_sched_barrier(0); }while(0)

// ---- ordered asm vmem helpers ----
__device__ __forceinline__ void ld4o(uint4& d, const u16* p, int imm){
  asm volatile("global_load_dwordx4 %0, %1, off offset:%2" : "=v"(d) : "v"(p), "i"(imm));
}
__device__ __forceinline__ void ld4co(uint4& d, const u16* p, int imm){
  asm volatile("global_load_dwordx4 %0, %1, off offset:%2 sc0 sc1" : "=v"(d) : "v"(p), "i"(imm));
}
__device__ __forceinline__ void ldg1f_off(float& d, const void* p, int byteoff){
  asm volatile("global_load_dword %0, %1, off offset:%2 sc0 sc1" : "=v"(d) : "v"(p), "i"(byteoff));
}
__device__ __forceinline__ void stg1f(void* p, float v){
  asm volatile("global_store_dword %0, %1, off sc0 sc1" :: "v"(p), "v"(v) : "memory");
}
__device__ __forceinline__ void stg1h(void* p, unsigned v){
  asm volatile("global_store_short %0, %1, off sc0 sc1" :: "v"(p), "v"(v) : "memory");
}
__device__ __forceinline__ void stg2(void* p, uint2 v){
  asm volatile("global_store_dwordx2 %0, %1, off sc0 sc1" :: "v"(p), "v"(v) : "memory");
}
__device__ __forceinline__ void vwait0(){
  asm volatile("s_waitcnt vmcnt(0)" ::: "memory");
  __builtin_amdgcn_sched_barrier(0);
}

// fence-free monotonic grid barrier (128 blocks co-resident by capacity).
__device__ __forceinline__ void gridbar(unsigned* bar, unsigned target){
  vwait0();                   // my coherent stores ack'd at the coherence point
  __syncthreads();
  if(threadIdx.x==0){
    __hip_atomic_fetch_add(bar, 1u, __ATOMIC_RELAXED, __HIP_MEMORY_SCOPE_AGENT);
    while(__hip_atomic_load(bar, __ATOMIC_RELAXED, __HIP_MEMORY_SCOPE_AGENT) < target)
      __builtin_amdgcn_s_sleep(4);
  }
  __syncthreads();
}

// issue one 64x128 A-chunk + B-chunk (8 ordered asm loads). chunk c:
// 0-3 = x (Wbig cols 512..), 4-7 = tadd (cols 1024..), 8-11 = h (cols 0..; B coherent)
__device__ __forceinline__ void issue_chunk(int c, uint4 (&rA)[4], uint4 (&rB)[4],
    const u16* gA, const u16* xs, const u16* ts, const u16* hs, int boff){
  int s=c>>2, kk=(c&3)*128;
  const u16* ga = gA + (s==0?512:(s==1?1024:0)) + kk;
  ld4o(rA[0],ga,0); ld4o(rA[1],ga,16); ld4o(rA[2],ga,32); ld4o(rA[3],ga,48);
  const u16* gb = (s==0?xs:(s==1?ts:hs)) + boff + kk;
  if(s<2){ ld4o(rB[0],gb,0); ld4o(rB[1],gb,16); ld4o(rB[2],gb,32); ld4o(rB[3],gb,48); }
  else   { ld4co(rB[0],gb,0); ld4co(rB[1],gb,16); ld4co(rB[2],gb,32); ld4co(rB[3],gb,48); }
}

__device__ __forceinline__ void write_chunk(u16* la, u16* lb, int off,
    const uint4 (&rA)[4], const uint4 (&rB)[4]){
  *(uint4*)&la[off]=rA[0]; *(uint4*)&la[off+8]=rA[1]; *(uint4*)&la[off+16]=rA[2]; *(uint4*)&la[off+24]=rA[3];
  *(uint4*)&lb[off]=rB[0]; *(uint4*)&lb[off+8]=rB[1]; *(uint4*)&lb[off+16]=rB[2]; *(uint4*)&lb[off+24]=rB[3];
}

__device__ __forceinline__ void mfma128(const u16* lA, const u16* lB, f32x4 (&acc)[2][2],
                                        int mw, int nw, int l16, int quad){
  #pragma unroll
  for(int ks=0;ks<4;ks++){
    bf16x8 a0=*(const bf16x8*)&lA[(mw+l16)*LP3+ks*32+quad*8];
    bf16x8 a1=*(const bf16x8*)&lA[(mw+16+l16)*LP3+ks*32+quad*8];
    bf16x8 b0=*(const bf16x8*)&lB[(nw+l16)*LP3+ks*32+quad*8];
    bf16x8 b1=*(const bf16x8*)&lB[(nw+16+l16)*LP3+ks*32+quad*8];
    acc[0][0]=__builtin_amdgcn_mfma_f32_16x16x32_bf16(a0,b0,acc[0][0],0,0,0);
    acc[0][1]=__builtin_amdgcn_mfma_f32_16x16x32_bf16(a0,b1,acc[0][1],0,0,0);
    acc[1][0]=__builtin_amdgcn_mfma_f32_16x16x32_bf16(a1,b0,acc[1][0],0,0,0);
    acc[1][1]=__builtin_amdgcn_mfma_f32_16x16x32_bf16(a1,b1,acc[1][1],0,0,0);
  }
}

// stage a 128x32 bf16 tile into LDS [128][LP] (k_T / k_y)
__device__ __forceinline__ void stage_tile(const u16* __restrict__ g, int row0, int k0,
                                           int rowstride, u16* l, int tid){
  #pragma unroll
  for(int id=tid; id<512; id+=256){
    int r=id>>2, c=id&3;
    *(uint4*)(&l[r*LP + c*8]) = *(const uint4*)(g + (size_t)(row0+r)*rowstride + k0 + c*8);
  }
}

__device__ __forceinline__ void mfma_tiles(const u16* lA, const u16* lB, f32x4 (&acc)[4][4],
                                           int mw, int nw, int l16, int quad){
  bf16x8 af[4], bfr[4];
  #pragma unroll
  for(int i=0;i<4;i++) af[i]  = *(const bf16x8*)(&lA[(mw+i*16+l16)*LP + quad*8]);
  #pragma unroll
  for(int j=0;j<4;j++) bfr[j] = *(const bf16x8*)(&lB[(nw+j*16+l16)*LP + quad*8]);
  #pragma unroll
  for(int i=0;i<4;i++)
    #pragma unroll
    for(int j=0;j<4;j++)
      acc[i][j] = __builtin_amdgcn_mfma_f32_16x16x32_bf16(af[i], bfr[j], acc[i][j], 0,0,0);
}

// ---------------- W2 = w_ti @ w_ht  (1536x512), fp32 ----------------
__global__ __launch_bounds__(256) void k_w2(const float* __restrict__ w_ti,
                                            const float* __restrict__ w_ht,
                                            float* __restrict__ W2){
  __shared__ float lA[64*17];
  __shared__ float lB[16*68];
  int tid=threadIdx.x, tx=tid&15, ty=tid>>4;
  int r0=blockIdx.x*64, n0=blockIdx.y*64;
  float acc[4][4]={};
  for(int k0=0;k0<512;k0+=16){
    __syncthreads();
    { int row=tid>>2, c=(tid&3)*4;
      float4 v=*(const float4*)(w_ti + (size_t)(r0+row)*512 + k0 + c);
      lA[row*17+c]=v.x; lA[row*17+c+1]=v.y; lA[row*17+c+2]=v.z; lA[row*17+c+3]=v.w; }
    { int kk=tid>>4, c=(tid&15)*4;
      float4 v=*(const float4*)(w_ht + (size_t)(k0+kk)*512 + n0 + c);
      lB[kk*68+c]=v.x; lB[kk*68+c+1]=v.y; lB[kk*68+c+2]=v.z; lB[kk*68+c+3]=v.w; }
    __syncthreads();
    for(int kk=0;kk<16;kk++){
      float a[4],b[4];
      #pragma unroll
      for(int i=0;i<4;i++) a[i]=lA[(ty*4+i)*17+kk];
      #pragma unroll
      for(int j=0;j<4;j++) b[j]=lB[kk*68+tx*4+j];
      #pragma unroll
      for(int i=0;i<4;i++)
        #pragma unroll
        for(int j=0;j<4;j++) acc[i][j]+=a[i]*b[j];
    }
  }
  #pragma unroll
  for(int i=0;i<4;i++)
    #pragma unroll
    for(int j=0;j<4;j++)
      W2[(size_t)(r0+ty*4+i)*512 + n0+tx*4+j]=acc[i][j];
}

// ---------------- prep: Wbig + bf16 weight copies + state init + barrier reset ----------------
__global__ __launch_bounds__(256) void k_prep(
  const float* __restrict__ w_ii, const float* __restrict__ w_hi, const float* __restrict__ w_ti,
  const float* __restrict__ w_co, const float* __restrict__ w_ht,
  const float* __restrict__ wyf, const float* __restrict__ wyc,
  const float* __restrict__ h0, const float* __restrict__ c0, const float* __restrict__ t0,
  const float* __restrict__ W2,
  u16* __restrict__ Wbig, u16* __restrict__ wcob, u16* __restrict__ whtb, u16* __restrict__ wyb,
  u16* __restrict__ hseq0, u16* __restrict__ tadd2b0, float* __restrict__ c_state,
  unsigned* __restrict__ bar)
{
  int i=blockIdx.x*256+threadIdx.x;
  if(i<1048576){
    int m=i>>9, k=i&511, r=m>>2, g=m&3;
    float v=w_hi[(size_t)(g*512+r)*512+k];
    if(g<3) v+=W2[(size_t)(g*512+r)*512+k];
    size_t o=(size_t)m*1536+k;
    Wbig[o]      =f2b(v);
    Wbig[o+512]  =f2b(w_ii[(size_t)(g*512+r)*512+k]);
    Wbig[o+1024] =f2b(g<3 ? w_ti[(size_t)(g*512+r)*512+k] : 0.f);
  }
  if(i<262144){ wcob[i]=f2b(w_co[i]); whtb[i]=f2b(w_ht[i]); }
  if(i<32768){ wyb[i]=f2b(wyf[i]); wyb[32768+i]=f2b(wyc[i]); }
  if(i<131072){
    int b=i>>9, h=i&511;
    hseq0[(size_t)b*512+h]  =f2b(h0[(size_t)h*256+b]);
    tadd2b0[(size_t)b*512+h]=f2b(t0[(size_t)h*256+b]);
    c_state[i]=c0[i];
  }
  if(i==0) *bar=0u;
}

// ---------------- tadd[t] ----------------
__global__ __launch_bounds__(256) void k_tadd(
  const float* __restrict__ lms, const float* __restrict__ pos, const float* __restrict__ caps,
  const float* __restrict__ w_lmt, const float* __restrict__ w_post, const float* __restrict__ w_capt,
  const float* __restrict__ b_i,
  u16* __restrict__ tadd_b, u16* __restrict__ tadd2b)
{
  __shared__ float lw[64*212];
  int t=blockIdx.y, h0=blockIdx.x*64, tid=threadIdx.x;
  for(int i=tid;i<64*200;i+=256){ int r=i/200, l=i-r*200; lw[r*212+l]    =w_lmt[(size_t)(h0+r)*200+l]; }
  for(int i=tid;i<64*6;  i+=256){ int r=i/6,   l=i-r*6;   lw[r*212+200+l]=w_post[(size_t)(h0+r)*6+l]; }
  for(int i=tid;i<64*3;  i+=256){ int r=i/3,   l=i-r*3;   lw[r*212+206+l]=w_capt[(size_t)(h0+r)*3+l]; }
  __syncthreads();
  int bx=(tid&63)*4, hy=(tid>>6)*16;
  float acc[16][4];
  #pragma unroll
  for(int j=0;j<16;j++){acc[j][0]=0;acc[j][1]=0;acc[j][2]=0;acc[j][3]=0;}
  const float* L=lms+(size_t)t*200*256;
  for(int l=0;l<200;l++){
    float4 v=*(const float4*)(L+(size_t)l*256+bx);
    #pragma unroll
    for(int j=0;j<16;j++){ float w=lw[(hy+j)*212+l];
      acc[j][0]+=w*v.x; acc[j][1]+=w*v.y; acc[j][2]+=w*v.z; acc[j][3]+=w*v.w; }
  }
  const float* P=pos+(size_t)t*6*256;
  for(int l=0;l<6;l++){
    float4 v=*(const float4*)(P+(size_t)l*256+bx);
    #pragma unroll
    for(int j=0;j<16;j++){ float w=lw[(hy+j)*212+200+l];
      acc[j][0]+=w*v.x; acc[j][1]+=w*v.y; acc[j][2]+=w*v.z; acc[j][3]+=w*v.w; }
  }
  const float* C=caps+(size_t)t*3*256;
  for(int l=0;l<3;l++){
    float4 v=*(const float4*)(C+(size_t)l*256+bx);
    #pragma unroll
    for(int j=0;j<16;j++){ float w=lw[(hy+j)*212+206+l];
      acc[j][0]+=w*v.x; acc[j][1]+=w*v.y; acc[j][2]+=w*v.z; acc[j][3]+=w*v.w; }
  }
  #pragma unroll
  for(int j=0;j<16;j++){
    int h=h0+hy+j;
    u16* d=tadd_b+(size_t)t*131072+(size_t)h*256+bx;
    d[0]=f2b(acc[j][0]); d[1]=f2b(acc[j][1]); d[2]=f2b(acc[j][2]); d[3]=f2b(acc[j][3]);
  }
  if(t<127){
    #pragma unroll
    for(int q=0;q<4;q++)
      #pragma unroll
      for(int j=0;j<16;j++){
        int h=h0+hy+j;
        tadd2b[(size_t)(t+1)*131072+(size_t)(bx+q)*512+h]=f2b(acc[j][q]+b_i[2048+h]);
      }
  }
}

// ---------------- x[t] ----------------
__global__ __launch_bounds__(256) void k_x(
  const float* __restrict__ inputs, const float* __restrict__ lms, const float* __restrict__ pos,
  const float* __restrict__ caps,
  const float* __restrict__ w_lmw, const float* __restrict__ w_posw, const float* __restrict__ w_capw,
  u16* __restrict__ xb)
{
  __shared__ float lw[64*212];
  int t=blockIdx.y, i0=blockIdx.x*64, tid=threadIdx.x;
  for(int i=tid;i<200*64;i+=256){ int l=i>>6, j=i&63; lw[j*212+l]    =w_lmw[(size_t)l*512+i0+j]; }
  for(int i=tid;i<6*64;  i+=256){ int l=i>>6, j=i&63; lw[j*212+200+l]=w_posw[(size_t)l*512+i0+j]; }
  for(int i=tid;i<3*64;  i+=256){ int l=i>>6, j=i&63; lw[j*212+206+l]=w_capw[(size_t)l*512+i0+j]; }
  __syncthreads();
  int bx=(tid&63)*4, hy=(tid>>6)*16;
  float acc[16][4];
  #pragma unroll
  for(int j=0;j<16;j++){acc[j][0]=0;acc[j][1]=0;acc[j][2]=0;acc[j][3]=0;}
  const float* L=lms+(size_t)t*200*256;
  for(int l=0;l<200;l++){
    float4 v=*(const float4*)(L+(size_t)l*256+bx);
    #pragma unroll
    for(int j=0;j<16;j++){ float w=lw[(hy+j)*212+l];
      acc[j][0]+=w*v.x; acc[j][1]+=w*v.y; acc[j][2]+=w*v.z; acc[j][3]+=w*v.w; }
  }
  const float* P=pos+(size_t)t*6*256;
  for(int l=0;l<6;l++){
    float4 v=*(const float4*)(P+(size_t)l*256+bx);
    #pragma unroll
    for(int j=0;j<16;j++){ float w=lw[(hy+j)*212+200+l];
      acc[j][0]+=w*v.x; acc[j][1]+=w*v.y; acc[j][2]+=w*v.z; acc[j][3]+=w*v.w; }
  }
  const float* C=caps+(size_t)t*3*256;
  for(int l=0;l<3;l++){
    float4 v=*(const float4*)(C+(size_t)l*256+bx);
    #pragma unroll
    for(int j=0;j<16;j++){ float w=lw[(hy+j)*212+206+l];
      acc[j][0]+=w*v.x; acc[j][1]+=w*v.y; acc[j][2]+=w*v.z; acc[j][3]+=w*v.w; }
  }
  #pragma unroll
  for(int j=0;j<16;j++){
    int ii=i0+hy+j;
    float4 inp=*(const float4*)(inputs+(size_t)t*131072+(size_t)ii*256+bx);
    acc[j][0]+=inp.x; acc[j][1]+=inp.y; acc[j][2]+=inp.z; acc[j][3]+=inp.w;
  }
  #pragma unroll
  for(int q=0;q<4;q++)
    #pragma unroll
    for(int j=0;j<16;j++){
      int ii=i0+hy+j;
      xb[(size_t)t*131072+(size_t)(bx+q)*512+ii]=f2b(acc[j][q]);
    }
}

// ---------------- persistent recurrence ----------------
__global__ __launch_bounds__(256) void k_rec(
  const u16* __restrict__ Wbig, const u16* __restrict__ wcob,
  const u16* __restrict__ xb, const u16* __restrict__ tadd2b,
  const float* __restrict__ b_i,
  float* __restrict__ c_state, float* __restrict__ preO,
  u16* __restrict__ c_bT, u16* __restrict__ hseq,
  unsigned* __restrict__ bar)
{
  __shared__ alignas(16) u16 sA0[64*LP3], sB0[64*LP3];
  __shared__ alignas(16) u16 sA1[64*LP3], sB1[64*LP3];
  __shared__ alignas(16) u16 lwco[32*520];
  int tid=threadIdx.x, lane=tid&63, wid=tid>>6;
  int l16=lane&15, quad=lane>>4;
  int bid=blockIdx.x;
  int m0=(bid>>2)*64, n0=(bid&3)*64;
  int mw=(wid>>1)*32, nw=(wid&1)*32;
  int bm0=(bid>>3)*32, bn0=(bid&7)*32;
  int bmw=(wid>>1)*16, bnw=(wid&1)*16;
  int nB=bn0+bnw+l16, mB=bm0+bmw+quad*4;
  int sr=tid>>2, sc3=(tid&3)*32;
  int asoff=sr*LP3+sc3;
  const u16* gA = Wbig + (size_t)(m0+sr)*1536 + sc3;
  int boff=(n0+sr)*512+sc3;
  const u16* cbr = c_bT + (size_t)nB*512 + quad*8;

  // stage w_co rows [bm0,bm0+32) into LDS once (removes compiler vmem from the loop)
  for(int i=tid;i<32*64;i+=256){ int r=i>>6, cg=i&63;
    *(uint4*)&lwco[r*520+cg*8] = *(const uint4*)(wcob + (size_t)(bm0+r)*512 + cg*8); }

  // biases + cell state into registers (constant addresses all steps)
  float bi[2][4]; int rh0[2];
  #pragma unroll
  for(int i=0;i<2;i++){ int rh=((m0+mw+i*16)>>2)+quad; rh0[i]=rh;
    bi[i][0]=b_i[rh]; bi[i][1]=b_i[512+rh]; bi[i][2]=b_i[1024+rh]; bi[i][3]=b_i[1536+rh]; }
  float creg[2][2];
  #pragma unroll
  for(int i=0;i<2;i++)
    #pragma unroll
    for(int j=0;j<2;j++) creg[i][j]=c_state[(size_t)rh0[i]*256 + (n0+nw+j*16+l16)];

  uint4 rA0[4],rB0[4],rA1[4],rB1[4];
  // prologue: chunk0,1 of t=0 (x segment)
  issue_chunk(0,rA0,rB0,gA,xb,xb,xb,boff);
  issue_chunk(1,rA1,rB1,gA,xb,xb,xb,boff);
  VMCNT(0);
  __syncthreads();

  unsigned ep=0;
  for(int t=0;t<128;t++){
    const u16* xs=xb    +(size_t)t*131072;
    const u16* ts=tadd2b+(size_t)t*131072;
    const u16* hs=hseq  +(size_t)t*131072;
    f32x4 acc[2][2]={};
    // chunk0 regs valid (drained at prev bar1 / prologue)
    write_chunk(sA0,sB0,asoff,rA0,rB0); LBAR();
    // ITER0 (chunk0 in lds0; hv store may be outstanding -> wait 9 = no-op)
    issue_chunk(2,rA0,rB0,gA,xs,ts,hs,boff);
    mfma128(sA0,sB0,acc,mw,nw,l16,quad);
    VMCNT(9);
    write_chunk(sA1,sB1,asoff,rA1,rB1); LBAR();
    // ITER1
    issue_chunk(3,rA1,rB1,gA,xs,ts,hs,boff);
    mfma128(sA1,sB1,acc,mw,nw,l16,quad);
    VMCNT(8);
    write_chunk(sA0,sB0,asoff,rA0,rB0); LBAR();
    // ITER2
    issue_chunk(4,rA0,rB0,gA,xs,ts,hs,boff);
    mfma128(sA0,sB0,acc,mw,nw,l16,quad);
    VMCNT(8);
    write_chunk(sA1,sB1,asoff,rA1,rB1); LBAR();
    // ITER3
    issue_chunk(5,rA1,rB1,gA,xs,ts,hs,boff);
    mfma128(sA1,sB1,acc,mw,nw,l16,quad);
    VMCNT(8);
    write_chunk(sA0,sB0,asoff,rA0,rB0); LBAR();
    // ITER4
    issue_chunk(6,rA0,rB0,gA,xs,ts,hs,boff);
    mfma128(sA0,sB0,acc,mw,nw,l16,quad);
    VMCNT(8);
    write_chunk(sA1,sB1,asoff,rA1,rB1); LBAR();
    // ITER5
    issue_chunk(7,rA1,rB1,gA,xs,ts,hs,boff);
    mfma128(sA1,sB1,acc,mw,nw,l16,quad);
    VMCNT(8);
    write_chunk(sA0,sB0,asoff,rA0,rB0); LBAR();
    // ITER6 (no issue: chunk8 is h, gated by midbar)
    mfma128(sA0,sB0,acc,mw,nw,l16,quad);
    VMCNT(0);
    write_chunk(sA1,sB1,asoff,rA1,rB1); LBAR();
    // ITER7
    mfma128(sA1,sB1,acc,mw,nw,l16,quad);
    // mid-step barrier: all blocks' phase B(t-1) done -> hseq[t] readable
    gridbar(bar, 128u*(++ep));
    issue_chunk(8,rA0,rB0,gA,xs,ts,hs,boff);
    issue_chunk(9,rA1,rB1,gA,xs,ts,hs,boff);
    VMCNT(8);
    write_chunk(sA0,sB0,asoff,rA0,rB0); LBAR();
    // ITER8
    issue_chunk(10,rA0,rB0,gA,xs,ts,hs,boff);
    mfma128(sA0,sB0,acc,mw,nw,l16,quad);
    VMCNT(8);
    write_chunk(sA1,sB1,asoff,rA1,rB1); LBAR();
    // ITER9
    issue_chunk(11,rA1,rB1,gA,xs,ts,hs,boff);
    mfma128(sA1,sB1,acc,mw,nw,l16,quad);
    VMCNT(8);
    write_chunk(sA0,sB0,asoff,rA0,rB0); LBAR();
    // ITER10
    mfma128(sA0,sB0,acc,mw,nw,l16,quad);
    VMCNT(0);
    write_chunk(sA1,sB1,asoff,rA1,rB1); LBAR();
    // ITER11
    mfma128(sA1,sB1,acc,mw,nw,l16,quad);

    // epilogue A: gates (permuted rows), c in regs, coherent stores
    #pragma unroll
    for(int i=0;i<2;i++){
      int rh=rh0[i];
      #pragma unroll
      for(int j=0;j<2;j++){
        int n=n0+nw+j*16+l16;
        float pi=acc[i][j][0]+bi[i][0];
        float pf=acc[i][j][1]+bi[i][1];
        float pz=acc[i][j][2]+bi[i][2];
        float po=acc[i][j][3]+bi[i][3];
        float ig=1.f/(1.f+__expf(-pi));
        float fg=1.f/(1.f+__expf(-pf));
        float zg=tanhf(pz);
        float cn_=fg*creg[i][j]+ig*zg;
        creg[i][j]=cn_;
        stg1f(c_state+(size_t)rh*256+n, cn_);
        stg1h(c_bT+(size_t)n*512+rh, (unsigned)f2b(cn_));
        stg1f(preO+(size_t)rh*256+n, po);
      }
    }
    // prefetch next step's chunk0/1 (x, stable) -- latency hides under bar1
    if(t<127){
      const u16* xn=xb+(size_t)(t+1)*131072;
      issue_chunk(0,rA0,rB0,gA,xn,xn,xn,boff);
      issue_chunk(1,rA1,rB1,gA,xn,xn,xn,boff);
    }
    gridbar(bar, 128u*(++ep));   // bar1: all epilogue stores visible; drains x01 too
    // phase B: o-GEMM, ordered coherent loads + counted waits, A from LDS
    float pre4[4], cc4[4];
    { const float* pb=preO   +(size_t)mB*256+nB;
      const float* cb=c_state+(size_t)mB*256+nB;
      ldg1f_off(pre4[0],pb,0); ldg1f_off(pre4[1],pb,1024);
      ldg1f_off(pre4[2],pb,2048); ldg1f_off(pre4[3],pb,3072);
      ldg1f_off(cc4[0],cb,0); ldg1f_off(cc4[1],cb,1024);
      ldg1f_off(cc4[2],cb,2048); ldg1f_off(cc4[3],cb,3072); }
    uint4 cbA[8], cbB[8];
    #pragma unroll
    for(int q8=0;q8<8;q8++) ld4co(cbA[q8], cbr, q8*64);
    #pragma unroll
    for(int q8=0;q8<8;q8++) ld4co(cbB[q8], cbr, 512+q8*64);
    f32x4 o4={};
    VMCNT(8);   // pre/cc + cbA done (cbB in flight)
    #pragma unroll
    for(int q8=0;q8<8;q8++){
      bf16x8 a=*(const bf16x8*)&lwco[(bmw+l16)*520 + q8*32 + quad*8];
      o4=__builtin_amdgcn_mfma_f32_16x16x32_bf16(a, *(bf16x8*)&cbA[q8], o4, 0,0,0);
    }
    VMCNT(0);   // cbB done
    #pragma unroll
    for(int q8=0;q8<8;q8++){
      bf16x8 a=*(const bf16x8*)&lwco[(bmw+l16)*520 + 256 + q8*32 + quad*8];
      o4=__builtin_amdgcn_mfma_f32_16x16x32_bf16(a, *(bf16x8*)&cbB[q8], o4, 0,0,0);
    }
    { u16x4 hv;
      #pragma unroll
      for(int rr=0;rr<4;rr++){
        float po=pre4[rr]+o4[rr];
        float o=1.f/(1.f+__expf(-po));
        hv[rr]=f2b(o*tanhf(cc4[rr]));
      }
      stg2(hseq+(size_t)(t+1)*131072+(size_t)nB*512+mB, *(uint2*)&hv);
    }
  }
}

// ---------------- T[t] = w_ht@h_t + b4 + tadd[t] -> out Ts (B,T,H) ----------------
__global__ __launch_bounds__(256) void k_T(
  const u16* __restrict__ whtb, const u16* __restrict__ hseq,
  const u16* __restrict__ tadd_b, const float* __restrict__ b_i,
  float* __restrict__ outTs)
{
  __shared__ alignas(16) u16 lA[128*LP];
  __shared__ alignas(16) u16 lB[128*LP];
  int tid=threadIdx.x, lane=tid&63, wid=tid>>6;
  int mw=(wid>>1)*64, nw=(wid&1)*64, l16=lane&15, quad=lane>>4;
  int m0=blockIdx.x*128, n0=blockIdx.y*128, t=blockIdx.z;
  const u16* hb=hseq+(size_t)(t+1)*131072;
  f32x4 acc[4][4]={};
  for(int k0=0;k0<512;k0+=32){
    __syncthreads();
    stage_tile(whtb,m0,k0,512,lA,tid);
    stage_tile(hb,n0,k0,512,lB,tid);
    __syncthreads();
    mfma_tiles(lA,lB,acc,mw,nw,l16,quad);
  }
  #pragma unroll
  for(int i=0;i<4;i++)
    #pragma unroll
    for(int j=0;j<4;j++){
      int n=n0+nw+j*16+l16;
      #pragma unroll
      for(int rr=0;rr<4;rr++){
        int m=m0+mw+i*16+quad*4+rr;
        float v=acc[i][j][rr]+b_i[2048+m]+b2f(tadd_b[(size_t)t*131072+(size_t)m*256+n]);
        outTs[(size_t)n*65536+(size_t)t*512+m]=v;
      }
    }
}

// ---------------- y_fact / y_cond ----------------
__global__ __launch_bounds__(256) void k_y(
  const u16* __restrict__ wyb, const float* __restrict__ Ts,
  const float* __restrict__ b_yf, const float* __restrict__ b_yc,
  float* __restrict__ oyf, float* __restrict__ oyc)
{
  __shared__ alignas(16) u16 lA[128*LP];
  __shared__ alignas(16) u16 lB[128*LP];
  int tid=threadIdx.x, lane=tid&63, wid=tid>>6;
  int mw=(wid>>1)*64, nw=(wid&1)*64, l16=lane&15, quad=lane>>4;
  int n0=blockIdx.x*128, t=blockIdx.y;
  f32x4 acc[4][4]={};
  for(int k0=0;k0<512;k0+=32){
    __syncthreads();
    stage_tile(wyb,0,k0,512,lA,tid);
    for(int id=tid;id<512;id+=256){
      int r=id>>2, c=(id&3)*8;
      const float* s=Ts + (size_t)(n0+r)*65536 + (size_t)t*512 + k0 + c;
      float4 v0=*(const float4*)s, v1=*(const float4*)(s+4);
      u16* d=&lB[r*LP+c];
      d[0]=f2b(v0.x); d[1]=f2b(v0.y); d[2]=f2b(v0.z); d[3]=f2b(v0.w);
      d[4]=f2b(v1.x); d[5]=f2b(v1.y); d[6]=f2b(v1.z); d[7]=f2b(v1.w);
    }
    __syncthreads();
    mfma_tiles(lA,lB,acc,mw,nw,l16,quad);
  }
  #pragma unroll
  for(int i=0;i<4;i++)
    #pragma unroll
    for(int j=0;j<4;j++){
      int n=n0+nw+j*16+l16;
      #pragma unroll
      for(int rr=0;rr<4;rr++){
        int m=mw+i*16+quad*4+rr;
        float v=acc[i][j][rr]+(m<64? b_yf[m] : b_yc[m-64]);
        if(m<64) oyf[(size_t)n*8192+(size_t)t*64+m]=v;
        else     oyc[(size_t)n*8192+(size_t)t*64+(m-64)]=v;
      }
    }
}

// ---------------- log_softmax over 64 tags ----------------
__global__ __launch_bounds__(256) void k_sm(const float* __restrict__ ysrc, float* __restrict__ dst){
  int wid=blockIdx.x*4+(threadIdx.x>>6);
  int lane=threadIdx.x&63;
  int tensor=wid>>15, bt=wid&32767;
  const float* s=ysrc+(size_t)tensor*2097152+(size_t)bt*64;
  float v=s[lane];
  float m=v;
  #pragma unroll
  for(int o=32;o;o>>=1) m=fmaxf(m,__shfl_xor(m,o,64));
  float e=__expf(v-m), sum=e;
  #pragma unroll
  for(int o=32;o;o>>=1) sum+=__shfl_xor(sum,o,64);
  dst[(size_t)tensor*2097152+(size_t)bt*64+lane]=v-m-__logf(sum);
}

extern "C" void kernel_launch(void* const* d_in, const int* in_sizes, int n_in,
                              void* d_out, int out_size, void* d_ws, size_t ws_size,
                              hipStream_t stream) {
  const float* inputs=(const float*)d_in[0];
  const float* lms   =(const float*)d_in[1];
  const float* pos   =(const float*)d_in[2];
  const float* caps  =(const float*)d_in[3];
  const float* h0    =(const float*)d_in[4];
  const float* c0    =(const float*)d_in[5];
  const float* t0    =(const float*)d_in[6];
  const float* w_ii  =(const float*)d_in[7];
  const float* w_hi  =(const float*)d_in[8];
  const float* w_ti  =(const float*)d_in[9];
  const float* w_co  =(const float*)d_in[10];
  const float* w_ht  =(const float*)d_in[11];
  const float* b_i   =(const float*)d_in[12];
  const float* wyf   =(const float*)d_in[13];
  const float* b_yf  =(const float*)d_in[14];
  const float* wyc   =(const float*)d_in[15];
  const float* b_yc  =(const float*)d_in[16];
  const float* w_lmw =(const float*)d_in[17];
  const float* w_posw=(const float*)d_in[18];
  const float* w_capw=(const float*)d_in[19];
  const float* w_lmt =(const float*)d_in[20];
  const float* w_post=(const float*)d_in[21];
  const float* w_capt=(const float*)d_in[22];

  char* ws=(char*)d_ws;
  float*    W2     =(float*)   (ws+0);          // 3,145,728
  u16*      Wbig   =(u16*)     (ws+3145728);    // 6,291,456
  u16*      wcob   =(u16*)     (ws+9437184);    //   524,288
  u16*      whtb   =(u16*)     (ws+9961472);    //   524,288
  u16*      wyb    =(u16*)     (ws+10485760);   //   131,072
  float*    c_state=(float*)   (ws+10616832);   //   524,288
  float*    preO   =(float*)   (ws+11141120);   //   524,288
  u16*      c_bT   =(u16*)     (ws+11665408);   //   262,144
  unsigned* bar    =(unsigned*)(ws+11927552);   //       128
  u16*      xb     =(u16*)     (ws+11927680);   // 33,554,432
  u16*      tadd_b =(u16*)     (ws+45482112);   // 33,554,432
  u16*      tadd2b =(u16*)     (ws+79036544);   // 33,554,432
  u16*      hseq   =(u16*)     (ws+112590976);  // 33,816,576  [129][256][512]; slot0=h0^T

  float* out=(float*)d_out;
  float* out_lf=out;
  float* out_yf=out+4194304;
  float* out_yc=out+6291456;
  float* out_Ts=out+8388608;

  k_w2  <<<dim3(24,8),256,0,stream>>>(w_ti,w_ht,W2);
  k_prep<<<4096,256,0,stream>>>(w_ii,w_hi,w_ti,w_co,w_ht,wyf,wyc,h0,c0,t0,W2,
                                Wbig,wcob,whtb,wyb,hseq,tadd2b,c_state,bar);
  k_tadd<<<dim3(8,128),256,0,stream>>>(lms,pos,caps,w_lmt,w_post,w_capt,b_i,tadd_b,tadd2b);
  k_x   <<<dim3(8,128),256,0,stream>>>(inputs,lms,pos,caps,w_lmw,w_posw,w_capw,xb);

  // plain launch: 128 blocks on 256 CUs -> co-resident by capacity
  k_rec<<<dim3(128),256,0,stream>>>(Wbig,wcob,xb,tadd2b,b_i,c_state,preO,c_bT,hseq,bar);

  k_T<<<dim3(4,2,128),256,0,stream>>>(whtb,hseq,tadd_b,b_i,out_Ts);
  k_y<<<dim3(2,128),256,0,stream>>>(wyb,out_Ts,b_yf,b_yc,out_yf,out_yc);
  k_sm<<<16384,256,0,stream>>>(out_yf,out_lf);
}